// Round 1
// baseline (4476.043 us; speedup 1.0000x reference)
//
#include <hip/hip_runtime.h>
#include <hip/hip_bf16.h>
#include <math.h>

#define B_  16
#define S_  512
#define D_  768
#define H_  12
#define L_  12
#define F_  3072
#define HD_ 64
#define T_  (B_ * S_)          // 8192 tokens
#define SCALE_ 0.125f          // HD^-0.5
#define EPS_ 1e-12f

typedef unsigned short u16;
typedef short  bf16x8 __attribute__((ext_vector_type(8)));
typedef float  f32x4  __attribute__((ext_vector_type(4)));

typedef const void __attribute__((address_space(1))) GVoid;
typedef void       __attribute__((address_space(3))) LVoid;

__device__ __forceinline__ u16 f2bf(float f) {
  unsigned u = __float_as_uint(f);
  u += 0x7fffu + ((u >> 16) & 1u);   // RNE
  return (u16)(u >> 16);
}

__device__ __forceinline__ void async16(void* lds, const void* g) {
  __builtin_amdgcn_global_load_lds((GVoid*)g, (LVoid*)lds, 16, 0, 0);
}

// ---------------------------------------------------------------- f32 -> bf16
__global__ void cvt_bf16(const float* __restrict__ in, u16* __restrict__ outp, long n) {
  long i = ((long)blockIdx.x * 256 + threadIdx.x) * 4;
  if (i >= n) return;
  float4 f = *(const float4*)(in + i);
  ushort4 o;
  o.x = f2bf(f.x); o.y = f2bf(f.y); o.z = f2bf(f.z); o.w = f2bf(f.w);
  *(ushort4*)(outp + i) = o;
}

// ---------------------------------------------------------------- block reduce
__device__ __forceinline__ float blk_sum(float v) {
  __shared__ float red[4];
  #pragma unroll
  for (int m = 32; m; m >>= 1) v += __shfl_xor(v, m);
  if ((threadIdx.x & 63) == 0) red[threadIdx.x >> 6] = v;
  __syncthreads();
  v = red[0] + red[1] + red[2] + red[3];
  __syncthreads();
  return v;
}

// ---------------------------------------------------------------- embedding+LN
__global__ void embed_ln(const int* __restrict__ tokens, const float* __restrict__ tok_emb,
                         const float* __restrict__ pos_emb, const float* __restrict__ sent_emb,
                         const float* __restrict__ w, const float* __restrict__ bb,
                         float* __restrict__ x32, u16* __restrict__ x16) {
  int t = blockIdx.x;
  int s = t & (S_ - 1);
  int tok = tokens[t];
  float v[3];
  float sum = 0.f;
  #pragma unroll
  for (int i = 0; i < 3; ++i) {
    int c = threadIdx.x + i * 256;
    v[i] = tok_emb[(size_t)tok * D_ + c] + pos_emb[s * D_ + c] + sent_emb[c];
    sum += v[i];
  }
  float mean = blk_sum(sum) * (1.f / D_);
  float var = 0.f;
  #pragma unroll
  for (int i = 0; i < 3; ++i) { float d = v[i] - mean; var += d * d; }
  var = blk_sum(var) * (1.f / D_);
  float rstd = rsqrtf(var + EPS_);
  #pragma unroll
  for (int i = 0; i < 3; ++i) {
    int c = threadIdx.x + i * 256;
    float y = (v[i] - mean) * rstd * w[c] + bb[c];
    x32[(size_t)t * D_ + c] = y;
    x16[(size_t)t * D_ + c] = f2bf(y);
  }
}

// ---------------------------------------------------------------- x = LN(x + y)
__global__ void add_ln(float* __restrict__ x32, u16* __restrict__ x16,
                       const float* __restrict__ y,
                       const float* __restrict__ w, const float* __restrict__ bb) {
  int t = blockIdx.x;
  float v[3];
  float sum = 0.f;
  #pragma unroll
  for (int i = 0; i < 3; ++i) {
    int c = threadIdx.x + i * 256;
    v[i] = x32[(size_t)t * D_ + c] + y[(size_t)t * D_ + c];
    sum += v[i];
  }
  float mean = blk_sum(sum) * (1.f / D_);
  float var = 0.f;
  #pragma unroll
  for (int i = 0; i < 3; ++i) { float d = v[i] - mean; var += d * d; }
  var = blk_sum(var) * (1.f / D_);
  float rstd = rsqrtf(var + EPS_);
  #pragma unroll
  for (int i = 0; i < 3; ++i) {
    int c = threadIdx.x + i * 256;
    float o = (v[i] - mean) * rstd * w[c] + bb[c];
    x32[(size_t)t * D_ + c] = o;
    x16[(size_t)t * D_ + c] = f2bf(o);
  }
}

// ---------------------------------------------------------------- GEMM  C = A * W^T + bias
// A: [M,K] bf16 row-major, W: [N,K] bf16 row-major (torch Linear layout).
// EPI: 0 = bf16 out, 1 = exact GELU -> bf16 out, 2 = f32 out (pre-residual).
// 128x128 tile, BK=64, 4 waves (2x2), each wave 64x64 via 4x4 16x16x32 MFMAs.
// LDS staged via global_load_lds(16B) with XOR-swizzled SOURCE (slot ^= row&7),
// fragment ds_read_b128 applies the same swizzle -> ~2-way (free) banks.
template<int EPI>
__global__ void gemm_bt(const u16* __restrict__ A, const u16* __restrict__ W,
                        const float* __restrict__ bias, void* __restrict__ outp,
                        int M, int N, int K) {
  __shared__ u16 As[128 * 64];
  __shared__ u16 Bs[128 * 64];
  const int tid  = threadIdx.x;
  const int lane = tid & 63;
  const int wid  = tid >> 6;
  const int m0 = blockIdx.y * 128;
  const int n0 = blockIdx.x * 128;

  const u16* asrc[4]; const u16* bsrc[4];
  u16* adst[4]; u16* bdst[4];
  #pragma unroll
  for (int i = 0; i < 4; ++i) {
    int row  = (i * 4 + wid) * 8 + (lane >> 3);
    int slot = (lane & 7) ^ (row & 7);            // pre-swizzled source column slot
    asrc[i] = A + (size_t)(m0 + row) * K + slot * 8;
    bsrc[i] = W + (size_t)(n0 + row) * K + slot * 8;
    adst[i] = &As[(i * 4 + wid) * 512];
    bdst[i] = &Bs[(i * 4 + wid) * 512];
  }

  f32x4 acc[4][4] = {};
  const int wr = wid >> 1, wc = wid & 1;

  for (int kb = 0; kb < K; kb += 64) {
    #pragma unroll
    for (int i = 0; i < 4; ++i) {
      async16(adst[i], asrc[i] + kb);
      async16(bdst[i], bsrc[i] + kb);
    }
    __syncthreads();
    #pragma unroll
    for (int ks = 0; ks < 2; ++ks) {
      bf16x8 af[4], bfr[4];
      #pragma unroll
      for (int m = 0; m < 4; ++m) {
        int row  = wr * 64 + m * 16 + (lane & 15);
        int slot = (ks * 4 + (lane >> 4)) ^ (row & 7);
        af[m] = *(const bf16x8*)&As[row * 64 + slot * 8];
      }
      #pragma unroll
      for (int n = 0; n < 4; ++n) {
        int row  = wc * 64 + n * 16 + (lane & 15);
        int slot = (ks * 4 + (lane >> 4)) ^ (row & 7);
        bfr[n] = *(const bf16x8*)&Bs[row * 64 + slot * 8];
      }
      #pragma unroll
      for (int m = 0; m < 4; ++m)
        #pragma unroll
        for (int n = 0; n < 4; ++n)
          acc[m][n] = __builtin_amdgcn_mfma_f32_16x16x32_bf16(af[m], bfr[n], acc[m][n], 0, 0, 0);
    }
    __syncthreads();
  }

  #pragma unroll
  for (int m = 0; m < 4; ++m) {
    int row = m0 + wr * 64 + m * 16 + ((lane >> 4) << 2);
    #pragma unroll
    for (int n = 0; n < 4; ++n) {
      int col = n0 + wc * 64 + n * 16 + (lane & 15);
      float bv = bias[col];
      #pragma unroll
      for (int r = 0; r < 4; ++r) {
        float v = acc[m][n][r] + bv;
        if (EPI == 1) v = 0.5f * v * (1.0f + erff(v * 0.70710678f));
        if (EPI == 2) ((float*)outp)[(size_t)(row + r) * N + col] = v;
        else          ((u16*) outp)[(size_t)(row + r) * N + col] = f2bf(v);
      }
    }
  }
}

// ---------------------------------------------------------------- fused attention
// grid (S/128, H, B); 4 waves x 32 q-rows. K/V tiles of 64 in LDS (K swizzled).
// Online softmax in f32; P goes through wave-private LDS (C-layout -> A-layout).
__global__ void attn(const u16* __restrict__ qkv, u16* __restrict__ outp) {
  __shared__ u16 Ks[64 * 64];
  __shared__ u16 Vs[64 * 64];
  __shared__ u16 Ps[4][32 * 64];
  const int tid  = threadIdx.x;
  const int lane = tid & 63;
  const int wid  = tid >> 6;
  const int h = blockIdx.y;
  const int b = blockIdx.z;
  const int q0 = blockIdx.x * 128 + wid * 32;
  const size_t rowbase = (size_t)b * S_;

  bf16x8 qf[2][2];
  #pragma unroll
  for (int mf = 0; mf < 2; ++mf)
    #pragma unroll
    for (int ks = 0; ks < 2; ++ks) {
      size_t r = rowbase + q0 + mf * 16 + (lane & 15);
      int c = h * HD_ + ks * 32 + ((lane >> 4) << 3);
      qf[mf][ks] = *(const bf16x8*)&qkv[r * (3 * D_) + c];
    }

  f32x4 o[2][4] = {};
  float mst[2][4], lst[2][4];
  #pragma unroll
  for (int mf = 0; mf < 2; ++mf)
    #pragma unroll
    for (int r = 0; r < 4; ++r) { mst[mf][r] = -3.0e38f; lst[mf][r] = 0.f; }

  for (int s0 = 0; s0 < S_; s0 += 64) {
    #pragma unroll
    for (int i = 0; i < 2; ++i) {
      int row  = (i * 4 + wid) * 8 + (lane >> 3);
      int slot = lane & 7;
      size_t tok = rowbase + s0 + row;
      async16(&Ks[(i * 4 + wid) * 512],
              &qkv[tok * (3 * D_) + D_     + h * HD_ + (((slot ^ (row & 7)) << 3))]);
      async16(&Vs[(i * 4 + wid) * 512],
              &qkv[tok * (3 * D_) + 2 * D_ + h * HD_ + (slot << 3)]);
    }
    __syncthreads();

    // S = Q K^T (C layout: col = s = n*16+(lane&15), row = q = (lane>>4)*4+reg)
    f32x4 sa[2][4] = {};
    #pragma unroll
    for (int ks = 0; ks < 2; ++ks) {
      bf16x8 kf[4];
      #pragma unroll
      for (int n = 0; n < 4; ++n) {
        int row  = n * 16 + (lane & 15);
        int slot = (ks * 4 + (lane >> 4)) ^ (row & 7);
        kf[n] = *(const bf16x8*)&Ks[row * 64 + slot * 8];
      }
      #pragma unroll
      for (int mf = 0; mf < 2; ++mf)
        #pragma unroll
        for (int n = 0; n < 4; ++n)
          sa[mf][n] = __builtin_amdgcn_mfma_f32_16x16x32_bf16(qf[mf][ks], kf[n], sa[mf][n], 0, 0, 0);
    }

    // online softmax (state lives at the rows this lane owns in C layout)
    #pragma unroll
    for (int mf = 0; mf < 2; ++mf)
      #pragma unroll
      for (int r = 0; r < 4; ++r) {
        #pragma unroll
        for (int n = 0; n < 4; ++n) sa[mf][n][r] *= SCALE_;
        float mx = fmaxf(fmaxf(sa[mf][0][r], sa[mf][1][r]),
                         fmaxf(sa[mf][2][r], sa[mf][3][r]));
        #pragma unroll
        for (int d = 1; d < 16; d <<= 1) mx = fmaxf(mx, __shfl_xor(mx, d));
        float mnew = fmaxf(mst[mf][r], mx);
        float sc = __expf(mst[mf][r] - mnew);
        float sum = 0.f;
        #pragma unroll
        for (int n = 0; n < 4; ++n) {
          float p = __expf(sa[mf][n][r] - mnew);
          sa[mf][n][r] = p;
          sum += p;
        }
        #pragma unroll
        for (int d = 1; d < 16; d <<= 1) sum += __shfl_xor(sum, d);
        lst[mf][r] = lst[mf][r] * sc + sum;
        mst[mf][r] = mnew;
        #pragma unroll
        for (int n = 0; n < 4; ++n) o[mf][n][r] *= sc;
      }

    // P: C layout -> wave-private LDS (swizzled rows) -> A-layout fragments
    #pragma unroll
    for (int mf = 0; mf < 2; ++mf)
      #pragma unroll
      for (int n = 0; n < 4; ++n)
        #pragma unroll
        for (int r = 0; r < 4; ++r) {
          int q = mf * 16 + ((lane >> 4) << 2) + r;
          int s = n * 16 + (lane & 15);
          int slot = (s >> 3) ^ (q & 7);
          Ps[wid][q * 64 + slot * 8 + (s & 7)] = f2bf(sa[mf][n][r]);
        }

    #pragma unroll
    for (int ks = 0; ks < 2; ++ks) {
      bf16x8 pf[2];
      #pragma unroll
      for (int mf = 0; mf < 2; ++mf) {
        int row  = mf * 16 + (lane & 15);
        int slot = (ks * 4 + (lane >> 4)) ^ (row & 7);
        pf[mf] = *(const bf16x8*)&Ps[wid][row * 64 + slot * 8];
      }
      bf16x8 vf[4];
      #pragma unroll
      for (int n = 0; n < 4; ++n) {
        int colv  = n * 16 + (lane & 15);
        int kbase = ks * 32 + ((lane >> 4) << 3);
        #pragma unroll
        for (int j = 0; j < 8; ++j)
          vf[n][j] = (short)Vs[(kbase + j) * 64 + colv];
      }
      #pragma unroll
      for (int mf = 0; mf < 2; ++mf)
        #pragma unroll
        for (int n = 0; n < 4; ++n)
          o[mf][n] = __builtin_amdgcn_mfma_f32_16x16x32_bf16(pf[mf], vf[n], o[mf][n], 0, 0, 0);
    }
    __syncthreads();
  }

  #pragma unroll
  for (int mf = 0; mf < 2; ++mf)
    #pragma unroll
    for (int n = 0; n < 4; ++n)
      #pragma unroll
      for (int r = 0; r < 4; ++r) {
        size_t row = rowbase + q0 + mf * 16 + ((lane >> 4) << 2) + r;
        int col = h * HD_ + n * 16 + (lane & 15);
        outp[row * D_ + col] = f2bf(o[mf][n][r] / lst[mf][r]);
      }
}

// ---------------------------------------------------------------- pooler
__global__ void pooler(const float* __restrict__ x32, const float* __restrict__ pw,
                       const float* __restrict__ pb, float* __restrict__ outp) {
  __shared__ float xr[D_];
  int b = blockIdx.x;
  for (int c = threadIdx.x; c < D_; c += 256) xr[c] = x32[(size_t)b * S_ * D_ + c];
  __syncthreads();
  for (int j = threadIdx.x; j < D_; j += 256) {
    float s = pb[j];
    const float* wr = pw + (size_t)j * D_;
    for (int k = 0; k < D_; ++k) s += xr[k] * wr[k];
    outp[b * D_ + j] = tanhf(s);
  }
}

// ---------------------------------------------------------------- launch
extern "C" void kernel_launch(void* const* d_in, const int* in_sizes, int n_in,
                              void* d_out, int out_size, void* d_ws, size_t ws_size,
                              hipStream_t stream) {
  (void)in_sizes; (void)n_in; (void)out_size; (void)ws_size;
  const int*   tokens   = (const int*)  d_in[0];
  const float* tok_emb  = (const float*)d_in[1];
  const float* pos_emb  = (const float*)d_in[2];
  const float* sent_emb = (const float*)d_in[3];
  const float* emb_ln_w = (const float*)d_in[4];
  const float* emb_ln_b = (const float*)d_in[5];
  const float* qkv_w    = (const float*)d_in[6];
  const float* qkv_b    = (const float*)d_in[7];
  const float* proj_w   = (const float*)d_in[8];
  const float* proj_b   = (const float*)d_in[9];
  const float* ln1_w    = (const float*)d_in[10];
  const float* ln1_b    = (const float*)d_in[11];
  const float* ln2_w    = (const float*)d_in[12];
  const float* ln2_b    = (const float*)d_in[13];
  const float* mlp_w1   = (const float*)d_in[14];
  const float* mlp_b1   = (const float*)d_in[15];
  const float* mlp_w2   = (const float*)d_in[16];
  const float* mlp_b2   = (const float*)d_in[17];
  const float* pool_w   = (const float*)d_in[18];
  const float* pool_b   = (const float*)d_in[19];

  char* ws = (char*)d_ws;
  size_t off = 0;
  auto alloc = [&](size_t bytes) { void* p = ws + off; off += (bytes + 255) & ~(size_t)255; return p; };
  u16*   WQ  = (u16*)  alloc((size_t)L_ * 3 * D_ * D_ * 2);
  u16*   WP  = (u16*)  alloc((size_t)L_ * D_ * D_ * 2);
  u16*   W1  = (u16*)  alloc((size_t)L_ * F_ * D_ * 2);
  u16*   W2  = (u16*)  alloc((size_t)L_ * D_ * F_ * 2);
  float* Xf  = (float*)alloc((size_t)T_ * D_ * 4);
  u16*   Xb  = (u16*)  alloc((size_t)T_ * D_ * 2);
  u16*   QKV = (u16*)  alloc((size_t)T_ * 3 * D_ * 2);
  u16*   AO  = (u16*)  alloc((size_t)T_ * D_ * 2);
  float* GO  = (float*)alloc((size_t)T_ * D_ * 4);
  u16*   Hb  = (u16*)  alloc((size_t)T_ * F_ * 2);

  // weights -> bf16 (re-done every call; ws is re-poisoned by harness)
  {
    long n;
    n = (long)L_ * 3 * D_ * D_;
    cvt_bf16<<<(unsigned)((n / 4 + 255) / 256), 256, 0, stream>>>(qkv_w, WQ, n);
    n = (long)L_ * D_ * D_;
    cvt_bf16<<<(unsigned)((n / 4 + 255) / 256), 256, 0, stream>>>(proj_w, WP, n);
    n = (long)L_ * F_ * D_;
    cvt_bf16<<<(unsigned)((n / 4 + 255) / 256), 256, 0, stream>>>(mlp_w1, W1, n);
    n = (long)L_ * D_ * F_;
    cvt_bf16<<<(unsigned)((n / 4 + 255) / 256), 256, 0, stream>>>(mlp_w2, W2, n);
  }

  embed_ln<<<T_, 256, 0, stream>>>(tokens, tok_emb, pos_emb, sent_emb,
                                   emb_ln_w, emb_ln_b, Xf, Xb);

  for (int l = 0; l < L_; ++l) {
    const u16* wq = WQ + (size_t)l * 3 * D_ * D_;
    const u16* wp = WP + (size_t)l * D_ * D_;
    const u16* w1 = W1 + (size_t)l * F_ * D_;
    const u16* w2 = W2 + (size_t)l * D_ * F_;

    gemm_bt<0><<<dim3(3 * D_ / 128, T_ / 128), 256, 0, stream>>>(
        Xb, wq, qkv_b + (size_t)l * 3 * D_, QKV, T_, 3 * D_, D_);

    attn<<<dim3(S_ / 128, H_, B_), 256, 0, stream>>>(QKV, AO);

    gemm_bt<2><<<dim3(D_ / 128, T_ / 128), 256, 0, stream>>>(
        AO, wp, proj_b + (size_t)l * D_, GO, T_, D_, D_);

    add_ln<<<T_, 256, 0, stream>>>(Xf, Xb, GO, ln1_w + (size_t)l * D_, ln1_b + (size_t)l * D_);

    gemm_bt<1><<<dim3(F_ / 128, T_ / 128), 256, 0, stream>>>(
        Xb, w1, mlp_b1 + (size_t)l * F_, Hb, T_, F_, D_);

    gemm_bt<2><<<dim3(D_ / 128, T_ / 128), 256, 0, stream>>>(
        Hb, w2, mlp_b2 + (size_t)l * D_, GO, T_, D_, F_);

    add_ln<<<T_, 256, 0, stream>>>(Xf, Xb, GO, ln2_w + (size_t)l * D_, ln2_b + (size_t)l * D_);
  }

  pooler<<<B_, 256, 0, stream>>>(Xf, pool_w, pool_b, (float*)d_out);
}

// Round 3
// 4272.248 us; speedup vs baseline: 1.0477x; 1.0477x over previous
//
#include <hip/hip_runtime.h>
#include <hip/hip_bf16.h>
#include <math.h>

#define B_  16
#define S_  512
#define D_  768
#define H_  12
#define L_  12
#define F_  3072
#define HD_ 64
#define T_  (B_ * S_)          // 8192 tokens
#define SCALE_ 0.125f          // HD^-0.5
#define EPS_ 1e-12f

typedef unsigned short u16;
typedef short  bf16x8 __attribute__((ext_vector_type(8)));
typedef float  f32x4  __attribute__((ext_vector_type(4)));

typedef const void __attribute__((address_space(1))) GVoid;
typedef void       __attribute__((address_space(3))) LVoid;

__device__ __forceinline__ u16 f2bf(float f) {
  unsigned u = __float_as_uint(f);
  u += 0x7fffu + ((u >> 16) & 1u);   // RNE
  return (u16)(u >> 16);
}

__device__ __forceinline__ void async16(void* lds, const void* g) {
  __builtin_amdgcn_global_load_lds((GVoid*)g, (LVoid*)lds, 16, 0, 0);
}

// ---------------------------------------------------------------- f32 -> bf16
__global__ void cvt_bf16(const float* __restrict__ in, u16* __restrict__ outp, long n) {
  long i = ((long)blockIdx.x * 256 + threadIdx.x) * 4;
  if (i >= n) return;
  float4 f = *(const float4*)(in + i);
  ushort4 o;
  o.x = f2bf(f.x); o.y = f2bf(f.y); o.z = f2bf(f.z); o.w = f2bf(f.w);
  *(ushort4*)(outp + i) = o;
}

// ---------------------------------------------------------------- block reduces
__device__ __forceinline__ float blk_sum4(float v) {   // 256 threads
  __shared__ float red[4];
  #pragma unroll
  for (int m = 32; m; m >>= 1) v += __shfl_xor(v, m);
  if ((threadIdx.x & 63) == 0) red[threadIdx.x >> 6] = v;
  __syncthreads();
  v = red[0] + red[1] + red[2] + red[3];
  __syncthreads();
  return v;
}

__device__ __forceinline__ float blk_sum3(float v) {   // 192 threads
  __shared__ float red[3];
  #pragma unroll
  for (int m = 32; m; m >>= 1) v += __shfl_xor(v, m);
  if ((threadIdx.x & 63) == 0) red[threadIdx.x >> 6] = v;
  __syncthreads();
  v = red[0] + red[1] + red[2];
  __syncthreads();
  return v;
}

// ---------------------------------------------------------------- embedding+LN
__global__ void embed_ln(const int* __restrict__ tokens, const float* __restrict__ tok_emb,
                         const float* __restrict__ pos_emb, const float* __restrict__ sent_emb,
                         const float* __restrict__ w, const float* __restrict__ bb,
                         float* __restrict__ x32, u16* __restrict__ x16) {
  int t = blockIdx.x;
  int s = t & (S_ - 1);
  int tok = tokens[t];
  float v[3];
  float sum = 0.f;
  #pragma unroll
  for (int i = 0; i < 3; ++i) {
    int c = threadIdx.x + i * 256;
    v[i] = tok_emb[(size_t)tok * D_ + c] + pos_emb[s * D_ + c] + sent_emb[c];
    sum += v[i];
  }
  float mean = blk_sum4(sum) * (1.f / D_);
  float var = 0.f;
  #pragma unroll
  for (int i = 0; i < 3; ++i) { float d = v[i] - mean; var += d * d; }
  var = blk_sum4(var) * (1.f / D_);
  float rstd = rsqrtf(var + EPS_);
  #pragma unroll
  for (int i = 0; i < 3; ++i) {
    int c = threadIdx.x + i * 256;
    float y = (v[i] - mean) * rstd * w[c] + bb[c];
    x32[(size_t)t * D_ + c] = y;
    x16[(size_t)t * D_ + c] = f2bf(y);
  }
}

// ---------------------------------------------------------------- x = LN(x + y)  (192 thr, float4)
__global__ void add_ln(float* __restrict__ x32, u16* __restrict__ x16,
                       const float* __restrict__ y,
                       const float* __restrict__ w, const float* __restrict__ bb) {
  int t = blockIdx.x;
  int c = threadIdx.x * 4;
  const float4 xv = *(const float4*)&x32[(size_t)t * D_ + c];
  const float4 yv = *(const float4*)&y  [(size_t)t * D_ + c];
  float v0 = xv.x + yv.x, v1 = xv.y + yv.y, v2 = xv.z + yv.z, v3 = xv.w + yv.w;
  float mean = blk_sum3(v0 + v1 + v2 + v3) * (1.f / D_);
  float d0 = v0 - mean, d1 = v1 - mean, d2 = v2 - mean, d3 = v3 - mean;
  float var = blk_sum3(d0 * d0 + d1 * d1 + d2 * d2 + d3 * d3) * (1.f / D_);
  float rstd = rsqrtf(var + EPS_);
  const float4 wv = *(const float4*)&w[c];
  const float4 bv = *(const float4*)&bb[c];
  float o0 = d0 * rstd * wv.x + bv.x;
  float o1 = d1 * rstd * wv.y + bv.y;
  float o2 = d2 * rstd * wv.z + bv.z;
  float o3 = d3 * rstd * wv.w + bv.w;
  float4 of = {o0, o1, o2, o3};
  *(float4*)&x32[(size_t)t * D_ + c] = of;
  ushort4 ob = {f2bf(o0), f2bf(o1), f2bf(o2), f2bf(o3)};
  *(ushort4*)&x16[(size_t)t * D_ + c] = ob;
}

// ---------------------------------------------------------------- GEMM  C = A * W^T + bias
// A: [M,K] bf16 row-major, W: [N,K] bf16 row-major. 128x128 tile, BK=64, 4 waves.
// EPI: 0 = bf16 out, 1 = exact GELU -> bf16, 2 = f32 out.
// XCD-chunked block swizzle for L2 reuse of A-panels / B matrix.
template<int EPI>
__global__ __launch_bounds__(256) void gemm_bt(const u16* __restrict__ A, const u16* __restrict__ W,
                        const float* __restrict__ bias, void* __restrict__ outp,
                        int M, int N, int K) {
  __shared__ u16 As[128 * 64];
  __shared__ u16 Bs[128 * 64];
  const int tid  = threadIdx.x;
  const int lane = tid & 63;
  const int wid  = tid >> 6;

  // bijective XCD chunking (m204)
  const int gx = gridDim.x;
  const int nwg = gx * gridDim.y;
  const int f = blockIdx.y * gx + blockIdx.x;
  const int q = nwg >> 3, r = nwg & 7, xc = f & 7, pos = f >> 3;
  const int logical = (xc < r ? xc * (q + 1) : r * (q + 1) + (xc - r) * q) + pos;
  const int m0 = (logical / gx) * 128;
  const int n0 = (logical % gx) * 128;

  const u16* asrc[4]; const u16* bsrc[4];
  u16* adst[4]; u16* bdst[4];
  #pragma unroll
  for (int i = 0; i < 4; ++i) {
    int row  = (i * 4 + wid) * 8 + (lane >> 3);
    int slot = (lane & 7) ^ (row & 7);            // pre-swizzled source column slot
    asrc[i] = A + (size_t)(m0 + row) * K + slot * 8;
    bsrc[i] = W + (size_t)(n0 + row) * K + slot * 8;
    adst[i] = &As[(i * 4 + wid) * 512];
    bdst[i] = &Bs[(i * 4 + wid) * 512];
  }

  f32x4 acc[4][4] = {};
  const int wr = wid >> 1, wc = wid & 1;

  for (int kb = 0; kb < K; kb += 64) {
    #pragma unroll
    for (int i = 0; i < 4; ++i) {
      async16(adst[i], asrc[i] + kb);
      async16(bdst[i], bsrc[i] + kb);
    }
    __syncthreads();
    #pragma unroll
    for (int ks = 0; ks < 2; ++ks) {
      bf16x8 af[4], bfr[4];
      #pragma unroll
      for (int m = 0; m < 4; ++m) {
        int row  = wr * 64 + m * 16 + (lane & 15);
        int slot = (ks * 4 + (lane >> 4)) ^ (row & 7);
        af[m] = *(const bf16x8*)&As[row * 64 + slot * 8];
      }
      #pragma unroll
      for (int n = 0; n < 4; ++n) {
        int row  = wc * 64 + n * 16 + (lane & 15);
        int slot = (ks * 4 + (lane >> 4)) ^ (row & 7);
        bfr[n] = *(const bf16x8*)&Bs[row * 64 + slot * 8];
      }
      #pragma unroll
      for (int m = 0; m < 4; ++m)
        #pragma unroll
        for (int n = 0; n < 4; ++n)
          acc[m][n] = __builtin_amdgcn_mfma_f32_16x16x32_bf16(af[m], bfr[n], acc[m][n], 0, 0, 0);
    }
    __syncthreads();
  }

  #pragma unroll
  for (int m = 0; m < 4; ++m) {
    int row = m0 + wr * 64 + m * 16 + ((lane >> 4) << 2);
    #pragma unroll
    for (int n = 0; n < 4; ++n) {
      int col = n0 + wc * 64 + n * 16 + (lane & 15);
      float bv = bias[col];
      #pragma unroll
      for (int r2 = 0; r2 < 4; ++r2) {
        float v = acc[m][n][r2] + bv;
        if (EPI == 1) v = 0.5f * v * (1.0f + erff(v * 0.70710678f));
        if (EPI == 2) ((float*)outp)[(size_t)(row + r2) * N + col] = v;
        else          ((u16*) outp)[(size_t)(row + r2) * N + col] = f2bf(v);
      }
    }
  }
}

// ---------------------------------------------------------------- fused attention v2
// grid 768 = 4 q-tiles x H x B, XCD-chunked so the 4 q-tiles of one (b,h) share an XCD.
// 2-phase pipeline: issue K async16 + V reg-loads for tile t+1 before computing tile t.
// One barrier per tile. V transposed into LDS (stride 72, 16B-slot XOR swizzle) ->
// PV fragments are clean ds_read_b128.
__global__ __launch_bounds__(256) void attn(const u16* __restrict__ qkv, u16* __restrict__ outp) {
  __shared__ u16 Ks[2][64 * 64];    // 16 KB, K tiles (swizzled like GEMM)
  __shared__ u16 Vt[2][64 * 72];    // 18.4 KB, V transposed [col][tok-slots]
  __shared__ u16 Ps[4][32 * 64];    // 16 KB, per-wave P scratch
  const int tid  = threadIdx.x;
  const int lane = tid & 63;
  const int wid  = tid >> 6;

  // XCD chunking: physical f -> logical so logical is contiguous per XCD (768/8 = 96)
  const int f = blockIdx.x;
  const int logical = (f & 7) * 96 + (f >> 3);
  const int qt = logical & 3;
  const int hb = logical >> 2;
  const int h  = hb % H_;
  const int b  = hb / H_;
  const int q0 = qt * 128 + wid * 32;
  const size_t rowbase = (size_t)b * S_;
  const int LDQ = 3 * D_;

  // Q fragments (registers)
  bf16x8 qf[2][2];
  #pragma unroll
  for (int mf = 0; mf < 2; ++mf)
    #pragma unroll
    for (int ks = 0; ks < 2; ++ks) {
      size_t rrow = rowbase + q0 + mf * 16 + (lane & 15);
      int c = h * HD_ + ks * 32 + ((lane >> 4) << 3);
      qf[mf][ks] = *(const bf16x8*)&qkv[rrow * LDQ + c];
    }

  const int vtok  = tid >> 3;          // 0..31
  const int vcol0 = (tid & 7) * 8;

  auto stageK = [&](int buf, int s0) {
    #pragma unroll
    for (int i = 0; i < 2; ++i) {
      int chunk = wid * 2 + i;
      int row   = chunk * 8 + (lane >> 3);
      int slot  = (lane & 7) ^ (row & 7);
      async16(&Ks[buf][chunk * 512],
              &qkv[(rowbase + s0 + row) * LDQ + D_ + h * HD_ + slot * 8]);
    }
  };
  auto loadV = [&](bf16x8* vr, int s0) {
    #pragma unroll
    for (int j = 0; j < 2; ++j)
      vr[j] = *(const bf16x8*)&qkv[(rowbase + s0 + vtok + 32 * j) * LDQ + 2 * D_ + h * HD_ + vcol0];
  };

  bf16x8 vreg[2][2];
  stageK(0, 0);
  loadV(vreg[0], 0);
  __syncthreads();                      // drains vmcnt -> tile 0 ready

  f32x4 o[2][4] = {};
  float mst[2][4], lst[2][4];
  #pragma unroll
  for (int mf = 0; mf < 2; ++mf)
    #pragma unroll
    for (int r = 0; r < 4; ++r) { mst[mf][r] = -3.0e38f; lst[mf][r] = 0.f; }

  #pragma unroll
  for (int t = 0; t < 8; ++t) {
    const int cur = t & 1, nxt = cur ^ 1;
    if (t < 7) {                        // prefetch tile t+1 (hidden under QK+softmax)
      stageK(nxt, (t + 1) * 64);
      loadV(vreg[nxt], (t + 1) * 64);
    }

    // ---- S = Q K^T on Ks[cur]
    f32x4 sa[2][4] = {};
    __builtin_amdgcn_s_setprio(1);
    #pragma unroll
    for (int ks = 0; ks < 2; ++ks) {
      bf16x8 kf[4];
      #pragma unroll
      for (int n = 0; n < 4; ++n) {
        int row  = n * 16 + (lane & 15);
        int slot = (ks * 4 + (lane >> 4)) ^ (row & 7);
        kf[n] = *(const bf16x8*)&Ks[cur][row * 64 + slot * 8];
      }
      #pragma unroll
      for (int mf = 0; mf < 2; ++mf)
        #pragma unroll
        for (int n = 0; n < 4; ++n)
          sa[mf][n] = __builtin_amdgcn_mfma_f32_16x16x32_bf16(qf[mf][ks], kf[n], sa[mf][n], 0, 0, 0);
    }
    __builtin_amdgcn_s_setprio(0);

    // ---- online softmax (C-layout rows this lane owns)
    #pragma unroll
    for (int mf = 0; mf < 2; ++mf)
      #pragma unroll
      for (int r = 0; r < 4; ++r) {
        #pragma unroll
        for (int n = 0; n < 4; ++n) sa[mf][n][r] *= SCALE_;
        float mx = fmaxf(fmaxf(sa[mf][0][r], sa[mf][1][r]),
                         fmaxf(sa[mf][2][r], sa[mf][3][r]));
        #pragma unroll
        for (int d = 1; d < 16; d <<= 1) mx = fmaxf(mx, __shfl_xor(mx, d));
        float mnew = fmaxf(mst[mf][r], mx);
        float sc = __expf(mst[mf][r] - mnew);
        float sum = 0.f;
        #pragma unroll
        for (int n = 0; n < 4; ++n) {
          float p = __expf(sa[mf][n][r] - mnew);
          sa[mf][n][r] = p;
          sum += p;
        }
        #pragma unroll
        for (int d = 1; d < 16; d <<= 1) sum += __shfl_xor(sum, d);
        lst[mf][r] = lst[mf][r] * sc + sum;
        mst[mf][r] = mnew;
        #pragma unroll
        for (int n = 0; n < 4; ++n) o[mf][n][r] *= sc;
      }

    // ---- V transpose-write to Vt[cur] (data loaded last iteration)
    #pragma unroll
    for (int j = 0; j < 2; ++j) {
      int tok = vtok + 32 * j;
      #pragma unroll
      for (int e = 0; e < 8; ++e) {
        int col = vcol0 + e;
        Vt[cur][col * 72 + (((tok >> 3) ^ (col & 7)) << 3) + (tok & 7)] =
            (u16)vreg[cur][j][e];
      }
    }

    // ---- P: C-layout -> wave-private LDS (swizzled) -> A-layout
    #pragma unroll
    for (int mf = 0; mf < 2; ++mf)
      #pragma unroll
      for (int n = 0; n < 4; ++n)
        #pragma unroll
        for (int r = 0; r < 4; ++r) {
          int qq = mf * 16 + ((lane >> 4) << 2) + r;
          int ss = n * 16 + (lane & 15);
          int slot = (ss >> 3) ^ (qq & 7);
          Ps[wid][qq * 64 + slot * 8 + (ss & 7)] = f2bf(sa[mf][n][r]);
        }

    __syncthreads();                    // Vt complete (all waves); drains next-tile loads too

    // ---- O += P V on Vt[cur]
    __builtin_amdgcn_s_setprio(1);
    #pragma unroll
    for (int ks = 0; ks < 2; ++ks) {
      bf16x8 pf[2];
      #pragma unroll
      for (int mf = 0; mf < 2; ++mf) {
        int row  = mf * 16 + (lane & 15);
        int slot = (ks * 4 + (lane >> 4)) ^ (row & 7);
        pf[mf] = *(const bf16x8*)&Ps[wid][row * 64 + slot * 8];
      }
      bf16x8 vf[4];
      #pragma unroll
      for (int n = 0; n < 4; ++n) {
        int colv = n * 16 + (lane & 15);
        int grp  = ks * 4 + (lane >> 4);
        vf[n] = *(const bf16x8*)&Vt[cur][colv * 72 + ((grp ^ (colv & 7)) << 3)];
      }
      #pragma unroll
      for (int mf = 0; mf < 2; ++mf)
        #pragma unroll
        for (int n = 0; n < 4; ++n)
          o[mf][n] = __builtin_amdgcn_mfma_f32_16x16x32_bf16(pf[mf], vf[n], o[mf][n], 0, 0, 0);
    }
    __builtin_amdgcn_s_setprio(0);
  }

  #pragma unroll
  for (int mf = 0; mf < 2; ++mf)
    #pragma unroll
    for (int n = 0; n < 4; ++n)
      #pragma unroll
      for (int r = 0; r < 4; ++r) {
        size_t row = rowbase + q0 + mf * 16 + ((lane >> 4) << 2) + r;
        int col = h * HD_ + n * 16 + (lane & 15);
        outp[row * D_ + col] = f2bf(o[mf][n][r] / lst[mf][r]);
      }
}

// ---------------------------------------------------------------- pooler
__global__ void pooler(const float* __restrict__ x32, const float* __restrict__ pw,
                       const float* __restrict__ pb, float* __restrict__ outp) {
  __shared__ float xr[D_];
  int b = blockIdx.x;
  for (int c = threadIdx.x; c < D_; c += 256) xr[c] = x32[(size_t)b * S_ * D_ + c];
  __syncthreads();
  for (int j = threadIdx.x; j < D_; j += 256) {
    float s = pb[j];
    const float* wr = pw + (size_t)j * D_;
    for (int k = 0; k < D_; ++k) s += xr[k] * wr[k];
    outp[b * D_ + j] = tanhf(s);
  }
}

// ---------------------------------------------------------------- launch
extern "C" void kernel_launch(void* const* d_in, const int* in_sizes, int n_in,
                              void* d_out, int out_size, void* d_ws, size_t ws_size,
                              hipStream_t stream) {
  (void)in_sizes; (void)n_in; (void)out_size; (void)ws_size;
  const int*   tokens   = (const int*)  d_in[0];
  const float* tok_emb  = (const float*)d_in[1];
  const float* pos_emb  = (const float*)d_in[2];
  const float* sent_emb = (const float*)d_in[3];
  const float* emb_ln_w = (const float*)d_in[4];
  const float* emb_ln_b = (const float*)d_in[5];
  const float* qkv_w    = (const float*)d_in[6];
  const float* qkv_b    = (const float*)d_in[7];
  const float* proj_w   = (const float*)d_in[8];
  const float* proj_b   = (const float*)d_in[9];
  const float* ln1_w    = (const float*)d_in[10];
  const float* ln1_b    = (const float*)d_in[11];
  const float* ln2_w    = (const float*)d_in[12];
  const float* ln2_b    = (const float*)d_in[13];
  const float* mlp_w1   = (const float*)d_in[14];
  const float* mlp_b1   = (const float*)d_in[15];
  const float* mlp_w2   = (const float*)d_in[16];
  const float* mlp_b2   = (const float*)d_in[17];
  const float* pool_w   = (const float*)d_in[18];
  const float* pool_b   = (const float*)d_in[19];

  char* ws = (char*)d_ws;
  size_t off = 0;
  auto alloc = [&](size_t bytes) { void* p = ws + off; off += (bytes + 255) & ~(size_t)255; return p; };
  u16*   WQ  = (u16*)  alloc((size_t)L_ * 3 * D_ * D_ * 2);
  u16*   WP  = (u16*)  alloc((size_t)L_ * D_ * D_ * 2);
  u16*   W1  = (u16*)  alloc((size_t)L_ * F_ * D_ * 2);
  u16*   W2  = (u16*)  alloc((size_t)L_ * D_ * F_ * 2);
  float* Xf  = (float*)alloc((size_t)T_ * D_ * 4);
  u16*   Xb  = (u16*)  alloc((size_t)T_ * D_ * 2);
  u16*   QKV = (u16*)  alloc((size_t)T_ * 3 * D_ * 2);
  u16*   AO  = (u16*)  alloc((size_t)T_ * D_ * 2);
  float* GO  = (float*)alloc((size_t)T_ * D_ * 4);
  u16*   Hb  = (u16*)  alloc((size_t)T_ * F_ * 2);

  {
    long n;
    n = (long)L_ * 3 * D_ * D_;
    cvt_bf16<<<(unsigned)((n / 4 + 255) / 256), 256, 0, stream>>>(qkv_w, WQ, n);
    n = (long)L_ * D_ * D_;
    cvt_bf16<<<(unsigned)((n / 4 + 255) / 256), 256, 0, stream>>>(proj_w, WP, n);
    n = (long)L_ * F_ * D_;
    cvt_bf16<<<(unsigned)((n / 4 + 255) / 256), 256, 0, stream>>>(mlp_w1, W1, n);
    n = (long)L_ * D_ * F_;
    cvt_bf16<<<(unsigned)((n / 4 + 255) / 256), 256, 0, stream>>>(mlp_w2, W2, n);
  }

  embed_ln<<<T_, 256, 0, stream>>>(tokens, tok_emb, pos_emb, sent_emb,
                                   emb_ln_w, emb_ln_b, Xf, Xb);

  for (int l = 0; l < L_; ++l) {
    const u16* wq = WQ + (size_t)l * 3 * D_ * D_;
    const u16* wp = WP + (size_t)l * D_ * D_;
    const u16* w1 = W1 + (size_t)l * F_ * D_;
    const u16* w2 = W2 + (size_t)l * D_ * F_;

    gemm_bt<0><<<dim3(3 * D_ / 128, T_ / 128), 256, 0, stream>>>(
        Xb, wq, qkv_b + (size_t)l * 3 * D_, QKV, T_, 3 * D_, D_);

    attn<<<768, 256, 0, stream>>>(QKV, AO);

    gemm_bt<2><<<dim3(D_ / 128, T_ / 128), 256, 0, stream>>>(
        AO, wp, proj_b + (size_t)l * D_, GO, T_, D_, D_);

    add_ln<<<T_, 192, 0, stream>>>(Xf, Xb, GO, ln1_w + (size_t)l * D_, ln1_b + (size_t)l * D_);

    gemm_bt<1><<<dim3(F_ / 128, T_ / 128), 256, 0, stream>>>(
        Xb, w1, mlp_b1 + (size_t)l * F_, Hb, T_, F_, D_);

    gemm_bt<2><<<dim3(D_ / 128, T_ / 128), 256, 0, stream>>>(
        Hb, w2, mlp_b2 + (size_t)l * D_, GO, T_, D_, F_);

    add_ln<<<T_, 192, 0, stream>>>(Xf, Xb, GO, ln2_w + (size_t)l * D_, ln2_b + (size_t)l * D_);
  }

  pooler<<<B_, 256, 0, stream>>>(Xf, pool_w, pool_b, (float*)d_out);
}